// Round 7
// baseline (622.814 us; speedup 1.0000x reference)
//
#include <hip/hip_runtime.h>

// DCRNN: 2x (bucketed SpMM -> fused MFMA GRU cell). N=50000, E=800000, D=64.
// CSR-build via atomic-free counting sort over 1024 dst-buckets.
#define NN 50000
#define NE 800000
#define DD 64
#define NT (NN / 16)      // 3125 node-tiles of 16
#define NBUK 1024         // dst buckets
#define BUCKN 49          // nodes per bucket: 1024*49 = 50176 >= 50000
#define EBLK 4096         // edges per binning block
#define NBBIN 196         // ceil(NE/EBLK)
#define SCN (NBUK * NBBIN)  // 200704 count cells
#define NSB 784           // SCN/256 scan blocks (exact)
#define CONVB 3173        // conversion blocks

typedef float     f32x4 __attribute__((ext_vector_type(4)));
typedef _Float16  f16x8 __attribute__((ext_vector_type(8)));
typedef _Float16  f16x4 __attribute__((ext_vector_type(4)));
typedef _Float16  f16x2 __attribute__((ext_vector_type(2)));

// ---------------------------------------------------------------------------
// prep: convert x [N,64] f32 -> fp16 + 4 weight mats -> fp16   ||   per-block
// LDS histogram of dst buckets -> SC[buk*NBBIN + blk] (counting-sort matrix,
// bucket-major for the scan). NO global atomics.
// ---------------------------------------------------------------------------
__global__ void prep_kernel(const float* __restrict__ x,
                            const float* __restrict__ w0, const float* __restrict__ w1,
                            const float* __restrict__ w2, const float* __restrict__ w3,
                            _Float16* __restrict__ xh, _Float16* __restrict__ wh,
                            const int* __restrict__ ei, unsigned* __restrict__ SC) {
    if (blockIdx.x < CONVB) {
        int i = blockIdx.x * 256 + threadIdx.x; // quad index
        const int XQ = NN * DD / 4;             // 800000 quads of x
        if (i < XQ) {
            float4 v = ((const float4*)x)[i];
            f16x4 o = { (_Float16)v.x, (_Float16)v.y, (_Float16)v.z, (_Float16)v.w };
            ((f16x4*)xh)[i] = o;
        } else {
            int wi = i - XQ;                    // 4 mats * 3072 quads
            if (wi >= 4 * 3072) return;
            int mat = wi / 3072, q = wi - mat * 3072;
            const float* s = mat == 0 ? w0 : mat == 1 ? w1 : mat == 2 ? w2 : w3;
            float4 v = ((const float4*)s)[q];
            f16x4 o = { (_Float16)v.x, (_Float16)v.y, (_Float16)v.z, (_Float16)v.w };
            ((f16x4*)(wh + mat * 12288))[q] = o;
        }
    } else {
        int blk = blockIdx.x - CONVB;
        __shared__ unsigned lcnt[NBUK];
        for (int i = threadIdx.x; i < NBUK; i += 256) lcnt[i] = 0;
        __syncthreads();
        int base = blk * EBLK;
        int lim = NE - base; if (lim > EBLK) lim = EBLK;
        for (int k = threadIdx.x; k < lim; k += 256) {
            unsigned dst = (unsigned)ei[NE + base + k];
            atomicAdd(&lcnt[dst / BUCKN], 1u);          // LDS atomic only
        }
        __syncthreads();
        for (int i = threadIdx.x; i < NBUK; i += 256)
            SC[i * NBBIN + blk] = lcnt[i];
    }
}

// ---------------------------------------------------------------------------
// Exact exclusive scan of SC[SCN] in-place (3 kernels).
// ---------------------------------------------------------------------------
__global__ void scan1_kernel(const unsigned* __restrict__ SC, unsigned* __restrict__ psum) {
    __shared__ unsigned red[256];
    int i = blockIdx.x * 256 + threadIdx.x;             // grid covers SCN exactly
    red[threadIdx.x] = SC[i];
    __syncthreads();
    for (int d = 128; d > 0; d >>= 1) {
        if (threadIdx.x < d) red[threadIdx.x] += red[threadIdx.x + d];
        __syncthreads();
    }
    if (threadIdx.x == 0) psum[blockIdx.x] = red[0];
}

__global__ void scan2_kernel(unsigned* __restrict__ psum) {
    __shared__ unsigned tmp[256];
    int t = threadIdx.x;
    unsigned running = 0;
    for (int c = 0; c < (NSB + 255) / 256; ++c) {
        int i = c * 256 + t;
        unsigned v = (i < NSB) ? psum[i] : 0;
        tmp[t] = v;
        __syncthreads();
        #pragma unroll
        for (int d = 1; d < 256; d <<= 1) {
            unsigned add = (t >= d) ? tmp[t - d] : 0;
            __syncthreads();
            tmp[t] += add;
            __syncthreads();
        }
        if (i < NSB) psum[i] = running + tmp[t] - v;    // exclusive
        unsigned tot = tmp[255];
        __syncthreads();
        running += tot;
    }
}

__global__ void scan3_kernel(unsigned* __restrict__ SC, const unsigned* __restrict__ psum) {
    __shared__ unsigned tmp[256];
    int t = threadIdx.x;
    int i = blockIdx.x * 256 + t;
    unsigned v = SC[i];
    tmp[t] = v;
    __syncthreads();
    #pragma unroll
    for (int d = 1; d < 256; d <<= 1) {
        unsigned add = (t >= d) ? tmp[t - d] : 0;
        __syncthreads();
        tmp[t] += add;
        __syncthreads();
    }
    SC[i] = psum[blockIdx.x] + tmp[t] - v;              // in-place exclusive
}

// ---------------------------------------------------------------------------
// place: each block re-reads its edge chunk; position = SC[buk*NBBIN+blk] +
// LDS-cursor rank. Exclusive exact positions -> NO global atomics. Payload:
// sp u32 = src | (dl<<16) (src<2^16, dl<49), sw = f16 weight. 6B/edge.
// ---------------------------------------------------------------------------
__global__ __launch_bounds__(256) void place_kernel(const int* __restrict__ ei,
                                                    const float* __restrict__ ew,
                                                    const unsigned* __restrict__ SC,
                                                    unsigned* __restrict__ sp,
                                                    _Float16* __restrict__ sw) {
    __shared__ unsigned lbase[NBUK];
    __shared__ unsigned lcur[NBUK];
    int blk = blockIdx.x;
    for (int i = threadIdx.x; i < NBUK; i += 256) {
        lbase[i] = SC[i * NBBIN + blk];
        lcur[i] = 0;
    }
    __syncthreads();
    int base = blk * EBLK;
    int lim = NE - base; if (lim > EBLK) lim = EBLK;
    for (int k = threadIdx.x; k < lim; k += 256) {
        int e = base + k;
        unsigned dst = (unsigned)ei[NE + e];
        unsigned buk = dst / BUCKN;
        unsigned dl  = dst - buk * BUCKN;
        unsigned r = atomicAdd(&lcur[buk], 1u);         // LDS atomic only
        unsigned pos = lbase[buk] + r;
        sp[pos] = (unsigned)ei[e] | (dl << 16);
        sw[pos] = (_Float16)ew[e];
    }
}

// ---------------------------------------------------------------------------
// aggr: one block per bucket. LDS f32 accumulators [49][64] (12.5KB), edges
// split contiguously across 4 waves, 8-deep gather pipeline, ds_add_f32
// accumulate (lane->consecutive banks: conflict-free), fp16 writeout.
// ---------------------------------------------------------------------------
__global__ __launch_bounds__(256) void aggr_kernel(const unsigned* __restrict__ SC,
                                                   const unsigned* __restrict__ sp,
                                                   const _Float16* __restrict__ sw,
                                                   const _Float16* __restrict__ xh,
                                                   _Float16* __restrict__ aggrh) {
    __shared__ float acc[BUCKN * DD];
    int b = blockIdx.x;
    for (int i = threadIdx.x; i < BUCKN * DD; i += 256) acc[i] = 0.f;
    __syncthreads();

    unsigned start = SC[b * NBBIN];
    unsigned end   = (b + 1 < NBUK) ? SC[(b + 1) * NBBIN] : NE;
    int cnt = (int)(end - start);
    int wid = threadIdx.x >> 6, lane = threadIdx.x & 63;
    const unsigned*  spb = sp + start;
    const _Float16*  swb = sw + start;

    int q  = (cnt + 3) >> 2;
    int i0 = wid * q;
    int i1 = i0 + q; if (i1 > cnt) i1 = cnt;
    for (int i = i0; i < i1; i += 8) {
        unsigned Pk[8]; float Wk[8];
        #pragma unroll
        for (int j = 0; j < 8; ++j) {
            int idx = (i + j < i1) ? i + j : i1 - 1;    // clamped, always valid
            Pk[j] = spb[idx];
            Wk[j] = (i + j < i1) ? (float)swb[idx] : 0.f;
        }
        float v[8];
        #pragma unroll
        for (int j = 0; j < 8; ++j) v[j] = (float)xh[(Pk[j] & 0xFFFFu) * DD + lane];
        #pragma unroll
        for (int j = 0; j < 8; ++j) atomicAdd(&acc[(Pk[j] >> 16) * DD + lane], v[j] * Wk[j]);
    }
    __syncthreads();

    for (int idx = threadIdx.x; idx < BUCKN * (DD / 2); idx += 256) {
        int r = idx >> 5, c2 = idx & 31;
        int node = b * BUCKN + r;
        if (node < NN) {
            f16x2 o = { (_Float16)acc[r * DD + c2 * 2], (_Float16)acc[r * DD + c2 * 2 + 1] };
            *(f16x2*)(aggrh + node * DD + c2 * 2) = o;
        }
    }
}

// ---------------------------------------------------------------------------
// Fused GRU cell with fp16 MFMA. One wave per 16-node tile.
// A/B fragments use the SAME k mapping (8 contiguous per lane) -> result exact
// under any HW per-lane k permutation. C/D: col=lane&15, row=(lane>>4)*4+reg.
// ---------------------------------------------------------------------------
__global__ __launch_bounds__(256) void gru_kernel(
    const _Float16* __restrict__ aggrh,  // [N,64] fp16 (from aggregation)
    const _Float16* __restrict__ hA,     // [N,64] fp16: h (x or h1)
    const _Float16* __restrict__ wih,    // [192*64] fp16
    const _Float16* __restrict__ whh,    // [192*64] fp16
    const float* __restrict__ bih, const float* __restrict__ bhh,
    float* __restrict__ outF,            // layer2: d_out f32 (or null)
    _Float16* __restrict__ outH)         // layer1: h1 fp16 (or null)
{
    // Weights in LDS, rows padded 64->72 halves (144B: 16B-aligned, 2-way banks = free)
    __shared__ _Float16 W[2 * 192 * 72];
    #pragma unroll
    for (int it = 0; it < 12; ++it) {
        int idx = threadIdx.x + it * 256;          // 3072 vec8 = 2 mats * 192 rows * 8
        int mat = idx >= 1536 ? 1 : 0;
        int lid = idx - mat * 1536;
        int o = lid >> 3, k8 = (lid & 7) << 3;
        f16x8 v = *(const f16x8*)((mat ? whh : wih) + o * 64 + k8);
        *(f16x8*)&W[mat * 13824 + o * 72 + k8] = v;
    }
    __syncthreads();

    int lane = threadIdx.x & 63;
    int tile = blockIdx.x * 4 + (threadIdx.x >> 6);
    if (tile >= NT) return;
    int base = tile << 4;
    int c = lane & 15, g = lane >> 4;

    // A fragments: lane holds row (base+c), k = s*32 + g*8 .. +7
    f16x8 Aa[2], Ah[2];
    {
        const _Float16* ap = aggrh + (base + c) * DD + g * 8;
        const _Float16* hp = hA    + (base + c) * DD + g * 8;
        #pragma unroll
        for (int s = 0; s < 2; ++s) {
            Aa[s] = *(const f16x8*)(ap + s * 32);
            Ah[s] = *(const f16x8*)(hp + s * 32);
        }
    }

    f32x4 acc[12], hn[4];
    #pragma unroll
    for (int t = 0; t < 12; ++t) acc[t] = f32x4{0.f, 0.f, 0.f, 0.f};
    #pragma unroll
    for (int t = 0; t < 4; ++t) hn[t] = f32x4{0.f, 0.f, 0.f, 0.f};

    // gi for all 12 out-tiles (o = t*16+c)
    #pragma unroll
    for (int t = 0; t < 12; ++t) {
        #pragma unroll
        for (int s = 0; s < 2; ++s) {
            f16x8 b = *(const f16x8*)&W[(t * 16 + c) * 72 + s * 32 + g * 8];
            acc[t] = __builtin_amdgcn_mfma_f32_16x16x32_f16(Aa[s], b, acc[t], 0, 0, 0);
        }
    }
    // gh for r,z tiles (0..7): accumulate into the same acc (only sum needed)
    #pragma unroll
    for (int t = 0; t < 8; ++t) {
        #pragma unroll
        for (int s = 0; s < 2; ++s) {
            f16x8 b = *(const f16x8*)&W[13824 + (t * 16 + c) * 72 + s * 32 + g * 8];
            acc[t] = __builtin_amdgcn_mfma_f32_16x16x32_f16(Ah[s], b, acc[t], 0, 0, 0);
        }
    }
    // gh for n tiles (8..11): separate h_n
    #pragma unroll
    for (int t = 0; t < 4; ++t) {
        #pragma unroll
        for (int s = 0; s < 2; ++s) {
            f16x8 b = *(const f16x8*)&W[13824 + ((t + 8) * 16 + c) * 72 + s * 32 + g * 8];
            hn[t] = __builtin_amdgcn_mfma_f32_16x16x32_f16(Ah[s], b, hn[t], 0, 0, 0);
        }
    }

    // biases (lane-local, d = j*16 + c)
    float br[4], bz[4], bi_[4], bh_[4];
    #pragma unroll
    for (int j = 0; j < 4; ++j) {
        int d = j * 16 + c;
        br[j] = bih[d] + bhh[d];
        bz[j] = bih[64 + d] + bhh[64 + d];
        bi_[j] = bih[128 + d];
        bh_[j] = bhh[128 + d];
    }

    // gates + output. C layout: row (node) = g*4+m, col (d-slot) = c.
    #pragma unroll
    for (int m = 0; m < 4; ++m) {
        int n = base + g * 4 + m;
        #pragma unroll
        for (int j = 0; j < 4; ++j) {
            int d = j * 16 + c;
            float rv = 1.f / (1.f + __expf(-(acc[j][m] + br[j])));
            float zv = 1.f / (1.f + __expf(-(acc[4 + j][m] + bz[j])));
            float nv = tanhf(acc[8 + j][m] + bi_[j] + rv * (hn[j][m] + bh_[j]));
            float hold = (float)hA[n * DD + d];
            float o = (1.f - zv) * nv + zv * hold;
            if (outF) outF[n * DD + d] = o;
            else      outH[n * DD + d] = (_Float16)o;
        }
    }
}

// ---------------------------------------------------------------------------
extern "C" void kernel_launch(void* const* d_in, const int* in_sizes, int n_in,
                              void* d_out, int out_size, void* d_ws, size_t ws_size,
                              hipStream_t stream) {
    const float* x    = (const float*)d_in[0];
    const int*   ei   = (const int*)d_in[1];     // [2,E] int32
    const float* ew   = (const float*)d_in[2];   // [E,1]
    const float* wih1 = (const float*)d_in[3];
    const float* whh1 = (const float*)d_in[4];
    const float* bih1 = (const float*)d_in[5];
    const float* bhh1 = (const float*)d_in[6];
    const float* wih2 = (const float*)d_in[7];
    const float* whh2 = (const float*)d_in[8];
    const float* bih2 = (const float*)d_in[9];
    const float* bhh2 = (const float*)d_in[10];
    float* out = (float*)d_out;

    // workspace layout (bytes), total ~24.9MB:
    //   xh 6.4M | h1h 6.4M | aggrh 6.4M | sp 3.2M | sw 1.6M | wh 98K
    //   SC 803K | psum 3.2K
    char* ws = (char*)d_ws;
    _Float16* xh    = (_Float16*)ws;
    _Float16* h1h   = (_Float16*)(ws + 6400000);
    _Float16* aggrh = (_Float16*)(ws + 12800000);
    unsigned* sp    = (unsigned*)(ws + 19200000);
    _Float16* sw    = (_Float16*)(ws + 22400000);
    _Float16* wh    = (_Float16*)(ws + 24000000);
    unsigned* SC    = (unsigned*)(ws + 24098304);
    unsigned* psum  = (unsigned*)(ws + 24901120);

    // convert (x + weights -> fp16) || per-block bucket histogram
    prep_kernel<<<CONVB + NBBIN, 256, 0, stream>>>(x, wih1, whh1, wih2, whh2,
                                                   xh, wh, ei, SC);
    // exact exclusive scan of SC (in-place)
    scan1_kernel<<<NSB, 256, 0, stream>>>(SC, psum);
    scan2_kernel<<<1, 256, 0, stream>>>(psum);
    scan3_kernel<<<NSB, 256, 0, stream>>>(SC, psum);
    // atomic-free placement into bucket-sorted edge arrays
    place_kernel<<<NBBIN, 256, 0, stream>>>(ei, ew, SC, sp, sw);

    // ---- layer 1 ----
    aggr_kernel<<<NBUK, 256, 0, stream>>>(SC, sp, sw, xh, aggrh);
    gru_kernel<<<(NT + 3) / 4, 256, 0, stream>>>(aggrh, xh,
                                                 wh, wh + 12288, bih1, bhh1,
                                                 nullptr, h1h);

    // ---- layer 2 ----
    aggr_kernel<<<NBUK, 256, 0, stream>>>(SC, sp, sw, h1h, aggrh);
    gru_kernel<<<(NT + 3) / 4, 256, 0, stream>>>(aggrh, h1h,
                                                 wh + 2 * 12288, wh + 3 * 12288, bih2, bhh2,
                                                 out, nullptr);
}

// Round 8
// 132.134 us; speedup vs baseline: 4.7135x; 4.7135x over previous
//
#include <hip/hip_runtime.h>

// DCRNN: 2x (node-sorted-gather SpMM -> fused MFMA GRU cell). N=50000, E=800000, D=64.
// CSR built via fully atomic-free two-pass counting sort (LDS atomics only):
//   prep: per-block LDS histogram over 1024 dst-buckets -> SC counts matrix
//   scan: exact exclusive scan of SC
//   place: bucket-sorted (src | dst-local<<16, w) arrays, exclusive positions
//   sort2: within-bucket 49-bin sort -> node-sorted pw[] (src:16|w-f16:16) + off[]
//   aggr: one wave per node, register accumulation, 8-deep gather pipeline
#define NN 50000
#define NE 800000
#define DD 64
#define NT (NN / 16)      // 3125 node-tiles of 16
#define NBUK 1024         // dst buckets
#define BUCKN 49          // nodes per bucket: 1024*49 = 50176 >= 50000
#define EBLK 4096         // edges per binning block
#define NBBIN 196         // ceil(NE/EBLK)
#define SCN (NBUK * NBBIN)  // 200704 count cells
#define NSB 784           // SCN/256 scan blocks (exact)
#define CONVB 3173        // conversion blocks

typedef float     f32x4 __attribute__((ext_vector_type(4)));
typedef _Float16  f16x8 __attribute__((ext_vector_type(8)));
typedef _Float16  f16x4 __attribute__((ext_vector_type(4)));

union h2u { _Float16 f; unsigned short u; };

// ---------------------------------------------------------------------------
// prep: convert x f32->fp16 + 4 weight mats -> fp16  ||  per-block LDS
// histogram of dst buckets -> SC[buk*NBBIN + blk]. LDS atomics only.
// ---------------------------------------------------------------------------
__global__ void prep_kernel(const float* __restrict__ x,
                            const float* __restrict__ w0, const float* __restrict__ w1,
                            const float* __restrict__ w2, const float* __restrict__ w3,
                            _Float16* __restrict__ xh, _Float16* __restrict__ wh,
                            const int* __restrict__ ei, unsigned* __restrict__ SC) {
    if (blockIdx.x < CONVB) {
        int i = blockIdx.x * 256 + threadIdx.x; // quad index
        const int XQ = NN * DD / 4;             // 800000 quads of x
        if (i < XQ) {
            float4 v = ((const float4*)x)[i];
            f16x4 o = { (_Float16)v.x, (_Float16)v.y, (_Float16)v.z, (_Float16)v.w };
            ((f16x4*)xh)[i] = o;
        } else {
            int wi = i - XQ;                    // 4 mats * 3072 quads
            if (wi >= 4 * 3072) return;
            int mat = wi / 3072, q = wi - mat * 3072;
            const float* s = mat == 0 ? w0 : mat == 1 ? w1 : mat == 2 ? w2 : w3;
            float4 v = ((const float4*)s)[q];
            f16x4 o = { (_Float16)v.x, (_Float16)v.y, (_Float16)v.z, (_Float16)v.w };
            ((f16x4*)(wh + mat * 12288))[q] = o;
        }
    } else {
        int blk = blockIdx.x - CONVB;
        __shared__ unsigned lcnt[NBUK];
        for (int i = threadIdx.x; i < NBUK; i += 256) lcnt[i] = 0;
        __syncthreads();
        int base = blk * EBLK;
        int lim = NE - base; if (lim > EBLK) lim = EBLK;
        for (int k = threadIdx.x; k < lim; k += 256) {
            unsigned dst = (unsigned)ei[NE + base + k];
            atomicAdd(&lcnt[dst / BUCKN], 1u);          // LDS atomic (u32, native)
        }
        __syncthreads();
        for (int i = threadIdx.x; i < NBUK; i += 256)
            SC[i * NBBIN + blk] = lcnt[i];
    }
}

// ---------------------------------------------------------------------------
// Exact exclusive scan of SC[SCN] in-place (3 kernels).
// ---------------------------------------------------------------------------
__global__ void scan1_kernel(const unsigned* __restrict__ SC, unsigned* __restrict__ psum) {
    __shared__ unsigned red[256];
    int i = blockIdx.x * 256 + threadIdx.x;             // grid covers SCN exactly
    red[threadIdx.x] = SC[i];
    __syncthreads();
    for (int d = 128; d > 0; d >>= 1) {
        if (threadIdx.x < d) red[threadIdx.x] += red[threadIdx.x + d];
        __syncthreads();
    }
    if (threadIdx.x == 0) psum[blockIdx.x] = red[0];
}

__global__ void scan2_kernel(unsigned* __restrict__ psum) {
    __shared__ unsigned tmp[256];
    int t = threadIdx.x;
    unsigned running = 0;
    for (int c = 0; c < (NSB + 255) / 256; ++c) {
        int i = c * 256 + t;
        unsigned v = (i < NSB) ? psum[i] : 0;
        tmp[t] = v;
        __syncthreads();
        #pragma unroll
        for (int d = 1; d < 256; d <<= 1) {
            unsigned add = (t >= d) ? tmp[t - d] : 0;
            __syncthreads();
            tmp[t] += add;
            __syncthreads();
        }
        if (i < NSB) psum[i] = running + tmp[t] - v;    // exclusive
        unsigned tot = tmp[255];
        __syncthreads();
        running += tot;
    }
}

__global__ void scan3_kernel(unsigned* __restrict__ SC, const unsigned* __restrict__ psum) {
    __shared__ unsigned tmp[256];
    int t = threadIdx.x;
    int i = blockIdx.x * 256 + t;
    unsigned v = SC[i];
    tmp[t] = v;
    __syncthreads();
    #pragma unroll
    for (int d = 1; d < 256; d <<= 1) {
        unsigned add = (t >= d) ? tmp[t - d] : 0;
        __syncthreads();
        tmp[t] += add;
        __syncthreads();
    }
    SC[i] = psum[blockIdx.x] + tmp[t] - v;              // in-place exclusive
}

// ---------------------------------------------------------------------------
// place: bucket-sorted arrays via exclusive positions (LDS cursors only).
// sp u32 = src | (dl<<16) (src<2^16, dl<49), sw = f16 weight.
// ---------------------------------------------------------------------------
__global__ __launch_bounds__(256) void place_kernel(const int* __restrict__ ei,
                                                    const float* __restrict__ ew,
                                                    const unsigned* __restrict__ SC,
                                                    unsigned* __restrict__ sp,
                                                    _Float16* __restrict__ sw) {
    __shared__ unsigned lbase[NBUK];
    __shared__ unsigned lcur[NBUK];
    int blk = blockIdx.x;
    for (int i = threadIdx.x; i < NBUK; i += 256) {
        lbase[i] = SC[i * NBBIN + blk];
        lcur[i] = 0;
    }
    __syncthreads();
    int base = blk * EBLK;
    int lim = NE - base; if (lim > EBLK) lim = EBLK;
    for (int k = threadIdx.x; k < lim; k += 256) {
        int e = base + k;
        unsigned dst = (unsigned)ei[NE + e];
        unsigned buk = dst / BUCKN;
        unsigned dl  = dst - buk * BUCKN;
        unsigned r = atomicAdd(&lcur[buk], 1u);         // LDS atomic only
        unsigned pos = lbase[buk] + r;
        sp[pos] = (unsigned)ei[e] | (dl << 16);
        sw[pos] = (_Float16)ew[e];
    }
}

// ---------------------------------------------------------------------------
// sort2: one block per bucket. 49-bin LDS histogram + rank -> node-sorted
// packed edges pw[] = src | (f16-weight-bits << 16), and per-node off[].
// ---------------------------------------------------------------------------
__global__ __launch_bounds__(256) void sort2_kernel(const unsigned* __restrict__ SC,
                                                    const unsigned* __restrict__ sp,
                                                    const _Float16* __restrict__ sw,
                                                    unsigned* __restrict__ pw,
                                                    int* __restrict__ off) {
    __shared__ unsigned hist[BUCKN], nbase[BUCKN], cur[BUCKN];
    int b = blockIdx.x;
    unsigned start = SC[b * NBBIN];
    unsigned end   = (b + 1 < NBUK) ? SC[(b + 1) * NBBIN] : NE;
    int cnt = (int)(end - start);
    if (threadIdx.x < BUCKN) { hist[threadIdx.x] = 0; cur[threadIdx.x] = 0; }
    __syncthreads();
    for (int k = threadIdx.x; k < cnt; k += 256)
        atomicAdd(&hist[sp[start + k] >> 16], 1u);      // LDS atomic
    __syncthreads();
    if (threadIdx.x == 0) {                             // tiny serial scan (49)
        unsigned run = 0;
        for (int i = 0; i < BUCKN; ++i) { nbase[i] = run; run += hist[i]; }
    }
    __syncthreads();
    if (threadIdx.x < BUCKN)
        off[b * BUCKN + threadIdx.x] = (int)(start + nbase[threadIdx.x]);
    for (int k = threadIdx.x; k < cnt; k += 256) {
        unsigned v = sp[start + k];
        unsigned dl = v >> 16;
        unsigned r = atomicAdd(&cur[dl], 1u);           // LDS atomic
        h2u c; c.f = sw[start + k];
        pw[start + nbase[dl] + r] = (v & 0xFFFFu) | ((unsigned)c.u << 16);
    }
}

// ---------------------------------------------------------------------------
// aggr: one wave per node, lane = d-channel, REGISTER accumulation (round-5
// structure — the proven one). 8-deep gather pipeline, clamp-masked tail,
// 4B/edge payload. No atomics of any kind.
// ---------------------------------------------------------------------------
__global__ __launch_bounds__(256) void aggr_kernel(const int* __restrict__ off,
                                                   const unsigned* __restrict__ pw,
                                                   const _Float16* __restrict__ xh,
                                                   _Float16* __restrict__ aggrh) {
    int wv = (blockIdx.x * 256 + threadIdx.x) >> 6;
    if (wv >= NN) return;
    int lane = threadIdx.x & 63;
    int s = off[wv], e = off[wv + 1];
    int n = e - s;
    const unsigned* p = pw + s;
    float acc = 0.f;
    for (int i = 0; i < n; i += 8) {
        unsigned P[8];
        #pragma unroll
        for (int j = 0; j < 8; ++j) {
            int idx = (i + j < n) ? i + j : n - 1;      // clamped, always valid
            P[j] = p[idx];
        }
        float a[8], w[8];
        #pragma unroll
        for (int j = 0; j < 8; ++j) a[j] = (float)xh[(P[j] & 0xFFFFu) * DD + lane];
        #pragma unroll
        for (int j = 0; j < 8; ++j) {
            h2u c; c.u = (unsigned short)(P[j] >> 16);
            w[j] = (i + j < n) ? (float)c.f : 0.f;
        }
        #pragma unroll
        for (int j = 0; j < 8; ++j) acc += a[j] * w[j];
    }
    aggrh[wv * DD + lane] = (_Float16)acc;
}

// ---------------------------------------------------------------------------
// Fused GRU cell with fp16 MFMA. One wave per 16-node tile.
// A/B fragments use the SAME k mapping (8 contiguous per lane) -> result exact
// under any HW per-lane k permutation. C/D: col=lane&15, row=(lane>>4)*4+reg.
// ---------------------------------------------------------------------------
__global__ __launch_bounds__(256) void gru_kernel(
    const _Float16* __restrict__ aggrh,  // [N,64] fp16 (from aggregation)
    const _Float16* __restrict__ hA,     // [N,64] fp16: h (x or h1)
    const _Float16* __restrict__ wih,    // [192*64] fp16
    const _Float16* __restrict__ whh,    // [192*64] fp16
    const float* __restrict__ bih, const float* __restrict__ bhh,
    float* __restrict__ outF,            // layer2: d_out f32 (or null)
    _Float16* __restrict__ outH)         // layer1: h1 fp16 (or null)
{
    // Weights in LDS, rows padded 64->72 halves (144B: 16B-aligned, 2-way banks = free)
    __shared__ _Float16 W[2 * 192 * 72];
    #pragma unroll
    for (int it = 0; it < 12; ++it) {
        int idx = threadIdx.x + it * 256;          // 3072 vec8 = 2 mats * 192 rows * 8
        int mat = idx >= 1536 ? 1 : 0;
        int lid = idx - mat * 1536;
        int o = lid >> 3, k8 = (lid & 7) << 3;
        f16x8 v = *(const f16x8*)((mat ? whh : wih) + o * 64 + k8);
        *(f16x8*)&W[mat * 13824 + o * 72 + k8] = v;
    }
    __syncthreads();

    int lane = threadIdx.x & 63;
    int tile = blockIdx.x * 4 + (threadIdx.x >> 6);
    if (tile >= NT) return;
    int base = tile << 4;
    int c = lane & 15, g = lane >> 4;

    // A fragments: lane holds row (base+c), k = s*32 + g*8 .. +7
    f16x8 Aa[2], Ah[2];
    {
        const _Float16* ap = aggrh + (base + c) * DD + g * 8;
        const _Float16* hp = hA    + (base + c) * DD + g * 8;
        #pragma unroll
        for (int s = 0; s < 2; ++s) {
            Aa[s] = *(const f16x8*)(ap + s * 32);
            Ah[s] = *(const f16x8*)(hp + s * 32);
        }
    }

    f32x4 acc[12], hn[4];
    #pragma unroll
    for (int t = 0; t < 12; ++t) acc[t] = f32x4{0.f, 0.f, 0.f, 0.f};
    #pragma unroll
    for (int t = 0; t < 4; ++t) hn[t] = f32x4{0.f, 0.f, 0.f, 0.f};

    // gi for all 12 out-tiles (o = t*16+c)
    #pragma unroll
    for (int t = 0; t < 12; ++t) {
        #pragma unroll
        for (int s = 0; s < 2; ++s) {
            f16x8 b = *(const f16x8*)&W[(t * 16 + c) * 72 + s * 32 + g * 8];
            acc[t] = __builtin_amdgcn_mfma_f32_16x16x32_f16(Aa[s], b, acc[t], 0, 0, 0);
        }
    }
    // gh for r,z tiles (0..7): accumulate into the same acc (only sum needed)
    #pragma unroll
    for (int t = 0; t < 8; ++t) {
        #pragma unroll
        for (int s = 0; s < 2; ++s) {
            f16x8 b = *(const f16x8*)&W[13824 + (t * 16 + c) * 72 + s * 32 + g * 8];
            acc[t] = __builtin_amdgcn_mfma_f32_16x16x32_f16(Ah[s], b, acc[t], 0, 0, 0);
        }
    }
    // gh for n tiles (8..11): separate h_n
    #pragma unroll
    for (int t = 0; t < 4; ++t) {
        #pragma unroll
        for (int s = 0; s < 2; ++s) {
            f16x8 b = *(const f16x8*)&W[13824 + ((t + 8) * 16 + c) * 72 + s * 32 + g * 8];
            hn[t] = __builtin_amdgcn_mfma_f32_16x16x32_f16(Ah[s], b, hn[t], 0, 0, 0);
        }
    }

    // biases (lane-local, d = j*16 + c)
    float br[4], bz[4], bi_[4], bh_[4];
    #pragma unroll
    for (int j = 0; j < 4; ++j) {
        int d = j * 16 + c;
        br[j] = bih[d] + bhh[d];
        bz[j] = bih[64 + d] + bhh[64 + d];
        bi_[j] = bih[128 + d];
        bh_[j] = bhh[128 + d];
    }

    // gates + output. C layout: row (node) = g*4+m, col (d-slot) = c.
    #pragma unroll
    for (int m = 0; m < 4; ++m) {
        int n = base + g * 4 + m;
        #pragma unroll
        for (int j = 0; j < 4; ++j) {
            int d = j * 16 + c;
            float rv = 1.f / (1.f + __expf(-(acc[j][m] + br[j])));
            float zv = 1.f / (1.f + __expf(-(acc[4 + j][m] + bz[j])));
            float nv = tanhf(acc[8 + j][m] + bi_[j] + rv * (hn[j][m] + bh_[j]));
            float hold = (float)hA[n * DD + d];
            float o = (1.f - zv) * nv + zv * hold;
            if (outF) outF[n * DD + d] = o;
            else      outH[n * DD + d] = (_Float16)o;
        }
    }
}

// ---------------------------------------------------------------------------
extern "C" void kernel_launch(void* const* d_in, const int* in_sizes, int n_in,
                              void* d_out, int out_size, void* d_ws, size_t ws_size,
                              hipStream_t stream) {
    const float* x    = (const float*)d_in[0];
    const int*   ei   = (const int*)d_in[1];     // [2,E] int32
    const float* ew   = (const float*)d_in[2];   // [E,1]
    const float* wih1 = (const float*)d_in[3];
    const float* whh1 = (const float*)d_in[4];
    const float* bih1 = (const float*)d_in[5];
    const float* bhh1 = (const float*)d_in[6];
    const float* wih2 = (const float*)d_in[7];
    const float* whh2 = (const float*)d_in[8];
    const float* bih2 = (const float*)d_in[9];
    const float* bhh2 = (const float*)d_in[10];
    float* out = (float*)d_out;

    // workspace (total ~22.7MB, < proven 26.3MB). aggrh ALIASES the
    // sp/sw/SC/psum pool — those are dead once sort2 completes (stream order).
    //   xh      @ 0          6,400,000
    //   h1h     @ 6,400,000  6,400,000
    //   pw      @ 12,800,000 3,200,000
    //   pool    @ 16,000,000 : sp 3.2M | sw 1.6M | SC 802,816 | psum 3,136
    //   aggrh   @ 16,000,000 6,400,000  (alias of pool)
    //   wh      @ 22,400,000 98,304
    //   off     @ 22,498,304 200,704
    char* ws = (char*)d_ws;
    _Float16* xh    = (_Float16*)ws;
    _Float16* h1h   = (_Float16*)(ws + 6400000);
    unsigned* pw    = (unsigned*)(ws + 12800000);
    unsigned* sp    = (unsigned*)(ws + 16000000);
    _Float16* sw    = (_Float16*)(ws + 19200000);
    unsigned* SC    = (unsigned*)(ws + 20800000);
    unsigned* psum  = (unsigned*)(ws + 21602816);
    _Float16* aggrh = (_Float16*)(ws + 16000000);   // alias: live after sort2
    _Float16* wh    = (_Float16*)(ws + 22400000);
    int*      off   = (int*)     (ws + 22498304);

    // convert (x + weights -> fp16) || per-block bucket histogram. No memsets.
    prep_kernel<<<CONVB + NBBIN, 256, 0, stream>>>(x, wih1, whh1, wih2, whh2,
                                                   xh, wh, ei, SC);
    // exact exclusive scan of SC (in-place)
    scan1_kernel<<<NSB, 256, 0, stream>>>(SC, psum);
    scan2_kernel<<<1, 256, 0, stream>>>(psum);
    scan3_kernel<<<NSB, 256, 0, stream>>>(SC, psum);
    // bucket-sorted placement, then within-bucket node sort -> pw/off
    place_kernel<<<NBBIN, 256, 0, stream>>>(ei, ew, SC, sp, sw);
    sort2_kernel<<<NBUK, 256, 0, stream>>>(SC, sp, sw, pw, off);

    // ---- layer 1 ----
    aggr_kernel<<<NN * 64 / 256, 256, 0, stream>>>(off, pw, xh, aggrh);
    gru_kernel<<<(NT + 3) / 4, 256, 0, stream>>>(aggrh, xh,
                                                 wh, wh + 12288, bih1, bhh1,
                                                 nullptr, h1h);

    // ---- layer 2 ----
    aggr_kernel<<<NN * 64 / 256, 256, 0, stream>>>(off, pw, h1h, aggrh);
    gru_kernel<<<(NT + 3) / 4, 256, 0, stream>>>(aggrh, h1h,
                                                 wh + 2 * 12288, wh + 3 * 12288, bih2, bhh2,
                                                 out, nullptr);
}